// Round 10
// baseline (105.199 us; speedup 1.0000x reference)
//
#include <hip/hip_runtime.h>
#include <hip/hip_bf16.h>

#define TDIM 1024
#define KDIM 32

typedef short bf16x8 __attribute__((ext_vector_type(8)));
typedef float f32x4  __attribute__((ext_vector_type(4)));

__device__ __forceinline__ unsigned short f2bf(float x) {
    __hip_bfloat16 h = __float2bfloat16(x);
    return *reinterpret_cast<unsigned short*>(&h);
}

__device__ __forceinline__ int read_len(const int* __restrict__ lengths32, int b) {
    // int64 little-endian: int32 view at odd index 1 is high word of lengths[0] == 0.
    // int32: lengths[1] in [1,1024], never 0.  (verified rounds 1-9)
    const bool is64 = (lengths32[1] == 0);
    int len = is64 ? lengths32[2 * b] : lengths32[b];
    return len < 1 ? 1 : (len > TDIM ? TDIM : len);
}

// ---------------- K1: multi-chain per-wave chunk kernel -------------------
// Each wave advances NCHAIN independent chunk-product chains in lockstep;
// per step: loads for all chains, then per-chain {A=Ef*d build, B=bf16(C),
// 4x MFMA, uniform-predicated writeback}. The other chains' work sits inside
// every chain's MFMA->cvt->MFMA dependency gap (R2-R9 invariant: ~700 cyc
// exposed per step with 1 chain/wave).
template<int CHS, int NCH, int NCHAIN, int WPB>
__global__ __launch_bounds__(64 * WPB, 2) void crf_chunk_multi(
    const float* __restrict__ emissions,    // [B, T, K]
    const int*   __restrict__ lengths32,
    const float* __restrict__ transitions,  // [K, K]
    unsigned int* __restrict__ Pout,        // [B][NCH][1024] bf16 as 512 dwords
    int*          __restrict__ toteOut)     // [B][NCH]
{
    constexpr int NSEG = CHS * KDIM / 256;          // per-chain 1KB DMA segs
    constexpr int TOT  = NCHAIN * CHS * KDIM / 256; // exp-pass f32x4 iters
    __shared__ float lds_all[WPB][NCHAIN][CHS * KDIM];

    const int wid  = threadIdx.x >> 6;
    const int lane = threadIdx.x & 63;
    const int n    = lane & 15;
    const int g    = (lane >> 4) & 3;
    const int ww   = blockIdx.x * WPB + wid;  // wave slot within batch
    const int b    = blockIdx.y;
    const int len  = read_len(lengths32, b);

    int cnt[NCHAIN], shf[NCHAIN];
    bool any = false;
#pragma unroll
    for (int j = 0; j < NCHAIN; ++j) {
        const int c  = ww * NCHAIN + j;
        const int t0 = 1 + c * CHS;
        int cc = len - t0; cc = cc > CHS ? CHS : cc; if (cc < 0) cc = 0;
        cnt[j] = cc;
        int sh = t0 + CHS - TDIM; shf[j] = sh > 0 ? sh : 0;
        any = any || (cc > 0);
    }
    if (!any) return;

    float* myl = &lds_all[wid][0][0];
#pragma unroll
    for (int j = 0; j < NCHAIN; ++j) {
        if (cnt[j] > 0) {
            const int c  = ww * NCHAIN + j;
            const int t0 = 1 + c * CHS;
            const float* src = emissions + ((size_t)b * TDIM + (t0 - shf[j])) * KDIM;
            float* dst = myl + j * CHS * KDIM;
#pragma unroll
            for (int s = 0; s < NSEG; ++s)
                __builtin_amdgcn_global_load_lds(
                    (const __attribute__((address_space(1))) void*)(src + s * 256 + lane * 4),
                    (__attribute__((address_space(3))) void*)(dst + s * 256), 16, 0, 0);
        }
    }

    // static E^T factors (A elem e <-> contraction row rho(g,e))
    f32x4 Ef00, Ef01, Ef10, Ef11;
#pragma unroll
    for (int e = 0; e < 4; ++e) {
        Ef00[e] = __expf(transitions[(4 * g + e) * KDIM + n]);
        Ef01[e] = __expf(transitions[(16 + 4 * g + e) * KDIM + n]);
        Ef10[e] = __expf(transitions[(4 * g + e) * KDIM + 16 + n]);
        Ef11[e] = __expf(transitions[(16 + 4 * g + e) * KDIM + 16 + n]);
    }

    asm volatile("s_waitcnt vmcnt(0)" ::: "memory");
    __builtin_amdgcn_sched_barrier(0);

    // exp pre-pass over the whole wave slice (dead-chain garbage harmless)
    f32x4* mylv = (f32x4*)myl;
#pragma unroll
    for (int r = 0; r < TOT; ++r) {
        f32x4 v = mylv[r * 64 + lane];
#pragma unroll
        for (int e = 0; e < 4; ++e) v[e] = __expf(v[e]);
        mylv[r * 64 + lane] = v;
    }
    asm volatile("s_waitcnt lgkmcnt(0)" ::: "memory");
    __builtin_amdgcn_sched_barrier(0);

    // per-chain running products (identity init)
    f32x4 C[NCHAIN][4];
#pragma unroll
    for (int j = 0; j < NCHAIN; ++j)
#pragma unroll
        for (int q = 0; q < 4; ++q) {
            float d = (4 * g + q == n) ? 1.0f : 0.0f;
            C[j][0][q] = d; C[j][3][q] = d; C[j][1][q] = 0.0f; C[j][2][q] = 0.0f;
        }
    float sf[NCHAIN]; int pend[NCHAIN], tote[NCHAIN];
#pragma unroll
    for (int j = 0; j < NCHAIN; ++j) { sf[j] = 1.0f; pend[j] = 0; tote[j] = 0; }

    const f32x4 zero = {0.0f, 0.0f, 0.0f, 0.0f};

    for (int gq = 0; gq < CHS / 4; ++gq) {
#pragma unroll
        for (int u = 0; u < 4; ++u) {
            const int tre = 4 * gq + u;
            // phase A: emission factors for all chains (branch-free)
            f32x4 e0[NCHAIN], e1[NCHAIN];
#pragma unroll
            for (int j = 0; j < NCHAIN; ++j) {
                int tt = tre + shf[j]; tt = tt > CHS - 1 ? CHS - 1 : tt;
                const f32x4* mj = mylv + j * (CHS * KDIM / 4);
                e0[j] = mj[tt * 8 + g];
                e1[j] = mj[tt * 8 + 4 + g];
            }
            // phase B: fold pending rescale at group start (predicated)
            if (u == 0) {
#pragma unroll
                for (int j = 0; j < NCHAIN; ++j) {
                    const bool al = tre < cnt[j];
                    const float s = al ? sf[j] : 1.0f;
#pragma unroll
                    for (int e = 0; e < 4; ++e) { e0[j][e] *= s; e1[j][e] *= s; }
                    tote[j] += al ? pend[j] : 0;
                }
            }
            // phase C/D: per chain A-build, B=bf16(C), MFMA, predicated commit
#pragma unroll
            for (int j = 0; j < NCHAIN; ++j) {
                f32x4 a00 = Ef00 * e0[j], a01 = Ef01 * e1[j];
                f32x4 a10 = Ef10 * e0[j], a11 = Ef11 * e1[j];
                bf16x8 A0, A1, B0, B1;
#pragma unroll
                for (int q = 0; q < 4; ++q) {
                    A0[q]     = (short)f2bf(a00[q]);
                    A0[q + 4] = (short)f2bf(a01[q]);
                    A1[q]     = (short)f2bf(a10[q]);
                    A1[q + 4] = (short)f2bf(a11[q]);
                    B0[q]     = (short)f2bf(C[j][0][q]);
                    B0[q + 4] = (short)f2bf(C[j][2][q]);
                    B1[q]     = (short)f2bf(C[j][1][q]);
                    B1[q + 4] = (short)f2bf(C[j][3][q]);
                }
                f32x4 n00 = __builtin_amdgcn_mfma_f32_16x16x32_bf16(A0, B0, zero, 0, 0, 0);
                f32x4 n01 = __builtin_amdgcn_mfma_f32_16x16x32_bf16(A0, B1, zero, 0, 0, 0);
                f32x4 n10 = __builtin_amdgcn_mfma_f32_16x16x32_bf16(A1, B0, zero, 0, 0, 0);
                f32x4 n11 = __builtin_amdgcn_mfma_f32_16x16x32_bf16(A1, B1, zero, 0, 0, 0);
                const bool al = tre < cnt[j];
#pragma unroll
                for (int q = 0; q < 4; ++q) {
                    C[j][0][q] = al ? n00[q] : C[j][0][q];
                    C[j][1][q] = al ? n01[q] : C[j][1][q];
                    C[j][2][q] = al ? n10[q] : C[j][2][q];
                    C[j][3][q] = al ? n11[q] : C[j][3][q];
                }
            }
            // phase E: refresh rescale factors at group end
            if (u == 3) {
#pragma unroll
                for (int j = 0; j < NCHAIN; ++j) {
                    int bits = __builtin_amdgcn_readfirstlane(__float_as_int(C[j][0][0]));
                    pend[j] = ((bits >> 23) & 255) - 127;
                    sf[j] = __uint_as_float((unsigned)(127 - pend[j]) << 23);
                }
            }
        }
    }

    // store alive chains: bf16 col-major, dword idx = col*16 + row/2
#pragma unroll
    for (int j = 0; j < NCHAIN; ++j) {
        if (cnt[j] > 0) {
            unsigned int* outP = Pout + ((size_t)b * NCH + ww * NCHAIN + j) * 512;
#pragma unroll
            for (int p = 0; p < 2; ++p) {
                int q = 2 * p;
                outP[n * 16        + (4 * g + q) / 2]      = (unsigned)f2bf(C[j][0][q]) | ((unsigned)f2bf(C[j][0][q + 1]) << 16);
                outP[(16 + n) * 16 + (4 * g + q) / 2]      = (unsigned)f2bf(C[j][1][q]) | ((unsigned)f2bf(C[j][1][q + 1]) << 16);
                outP[n * 16        + (16 + 4 * g + q) / 2] = (unsigned)f2bf(C[j][2][q]) | ((unsigned)f2bf(C[j][2][q + 1]) << 16);
                outP[(16 + n) * 16 + (16 + 4 * g + q) / 2] = (unsigned)f2bf(C[j][3][q]) | ((unsigned)f2bf(C[j][3][q + 1]) << 16);
            }
            if (lane == 0) toteOut[b * NCH + ww * NCHAIN + j] = tote[j];
        }
    }
}

// ---------------- K2: chain chunk matrices through alpha ------------------
template<int NCH, int CHS>
__global__ __launch_bounds__(64) void crf_combine_kernel(
    const float* __restrict__ emissions,
    const int*   __restrict__ lengths32,
    const float* __restrict__ head_t,
    const float* __restrict__ last_t,
    const unsigned short* __restrict__ Pbuf,  // [B][NCH][1024] bf16 col-major
    const int*   __restrict__ toteBuf,
    float*       __restrict__ out)
{
    const int b    = blockIdx.x;
    const int lane = threadIdx.x;
    const int j    = lane & 31;

    const int len = read_len(lengths32, b);
    int nAlive = (len - 1 + CHS - 1) / CHS;
    if (nAlive > NCH) nAlive = NCH;

    float alpha = __expf(head_t[j] + emissions[(size_t)b * TDIM * KDIM + j]);
    int tote = 0;

    const char* base = (const char*)(Pbuf + (size_t)b * NCH * 1024);

    auto LOADC = [&](int cix, uint4 dst[4]) {
        int cc = cix < NCH ? cix : NCH - 1;
        const uint4* pc = (const uint4*)(base + (size_t)cc * 2048 + (size_t)j * 64);
#pragma unroll
        for (int w = 0; w < 4; ++w) dst[w] = pc[w];
    };

    uint4 cur[4], nx1[4];
    LOADC(0, cur);
    LOADC(1, nx1);

    for (int cix = 0; cix < nAlive; ++cix) {
        uint4 nx2[4];
        LOADC(cix + 2, nx2);

        float a0 = 0.0f, a1 = 0.0f;
#pragma unroll
        for (int w = 0; w < 4; ++w) {
            unsigned d[4] = {cur[w].x, cur[w].y, cur[w].z, cur[w].w};
#pragma unroll
            for (int h = 0; h < 4; ++h) {
                int r = w * 8 + h * 2;
                float plo = __uint_as_float(d[h] << 16);           // row r,   col j
                float phi = __uint_as_float(d[h] & 0xffff0000u);   // row r+1, col j
                float al  = __int_as_float(__builtin_amdgcn_readlane(__float_as_int(alpha), r));
                float ah  = __int_as_float(__builtin_amdgcn_readlane(__float_as_int(alpha), r + 1));
                a0 = fmaf(plo, al, a0);
                a1 = fmaf(phi, ah, a1);
            }
        }
        float acc = a0 + a1;
        int bits = __builtin_amdgcn_readfirstlane(__float_as_int(acc));
        int s = ((bits >> 23) & 255) - 127;
        alpha = acc * __uint_as_float((unsigned)(127 - s) << 23);
        tote += s + toteBuf[b * NCH + cix];
#pragma unroll
        for (int w = 0; w < 4; ++w) { cur[w] = nx1[w]; nx1[w] = nx2[w]; }
    }

    float pp = alpha * __expf(last_t[j]);
#pragma unroll
    for (int mm = 16; mm >= 1; mm >>= 1)
        pp += __shfl_xor(pp, mm, 64);

    if (lane == 0)
        out[b] = __logf(pp) + (float)tote * 0.69314718055994531f;
}

extern "C" void kernel_launch(void* const* d_in, const int* in_sizes, int n_in,
                              void* d_out, int out_size, void* d_ws, size_t ws_size,
                              hipStream_t stream)
{
    const float* emissions   = (const float*)d_in[0];
    const int*   lengths     = (const int*)d_in[1];
    const float* transitions = (const float*)d_in[2];
    const float* head_t      = (const float*)d_in[3];
    const float* last_t      = (const float*)d_in[4];
    float* out = (float*)d_out;
    const int B = out_size;  // 512

    unsigned int* Pbuf = (unsigned int*)d_ws;

    const size_t need32 = (size_t)B * 32 * 2048 + (size_t)B * 32 * 4;
    if (ws_size >= need32) {
        int* toteBf = (int*)((char*)d_ws + (size_t)B * 32 * 2048);
        // CHS=32, NCH=32, 4 chains/wave, 2 waves/block: grid (32/(4*2)=4, B)
        dim3 g1(4, B);
        crf_chunk_multi<32, 32, 4, 2><<<g1, 128, 0, stream>>>(emissions, lengths, transitions, Pbuf, toteBf);
        crf_combine_kernel<32, 32><<<B, 64, 0, stream>>>(emissions, lengths, head_t, last_t,
                                                         (const unsigned short*)Pbuf, toteBf, out);
    } else {
        int* toteBf = (int*)((char*)d_ws + (size_t)B * 16 * 2048);
        // fallback: CHS=64, NCH=16, 2 chains/wave, 2 waves/block: grid (16/(2*2)=4, B)
        dim3 g1(4, B);
        crf_chunk_multi<64, 16, 2, 2><<<g1, 128, 0, stream>>>(emissions, lengths, transitions, Pbuf, toteBf);
        crf_combine_kernel<16, 64><<<B, 64, 0, stream>>>(emissions, lengths, head_t, last_t,
                                                         (const unsigned short*)Pbuf, toteBf, out);
    }
}

// Round 12
// 86.293 us; speedup vs baseline: 1.2191x; 1.2191x over previous
//
#include <hip/hip_runtime.h>
#include <hip/hip_bf16.h>

#define TDIM 1024
#define KDIM 32

typedef short bf16x8 __attribute__((ext_vector_type(8)));
typedef float f32x4  __attribute__((ext_vector_type(4)));

// f32 pair -> packed bf16x2 via bias round-half-up + byte-perm (3 VALU, no asm).
// dst low16 = bf16(lo), high16 = bf16(hi). Values here are positive finite
// (products of exps, power-of-2 rescaled), so half-up vs RNE is <=1 ulp on ties.
__device__ __forceinline__ unsigned pk_pair(float lo, float hi) {
    unsigned ul = __float_as_uint(lo) + 0x8000u;
    unsigned uh = __float_as_uint(hi) + 0x8000u;
    return __builtin_amdgcn_perm(uh, ul, 0x07060302u);  // {uh[31:16], ul[31:16]}
}
__device__ __forceinline__ bf16x8 pk8(f32x4 lo, f32x4 hi) {
    union { unsigned u[4]; bf16x8 v; } x;
    x.u[0] = pk_pair(lo[0], lo[1]); x.u[1] = pk_pair(lo[2], lo[3]);
    x.u[2] = pk_pair(hi[0], hi[1]); x.u[3] = pk_pair(hi[2], hi[3]);
    return x.v;
}

__device__ __forceinline__ int read_len(const int* __restrict__ lengths32, int b) {
    // int64 little-endian: int32 view at odd index 1 is high word of lengths[0] == 0.
    // int32: lengths[1] in [1,1024], never 0.  (verified rounds 1-10)
    const bool is64 = (lengths32[1] == 0);
    int len = is64 ? lengths32[2 * b] : lengths32[b];
    return len < 1 ? 1 : (len > TDIM ? TDIM : len);
}

// ---------------- K1: dual-chain per-wave chunk kernel --------------------
// Wave w owns adjacent chunks (2w, 2w+1): two independent product chains
// interleaved for ILP (cntB>0 => cntA full => tails wave-uniform, off hot
// path). Per chain-step: 16 f32 mul + 16 pk_pair (48 VALU) + 4 MFMA
// (intrinsic: compiler handles MFMA hazards). B-operand = pk8(prev C) is the
// only work on the MFMA->MFMA chain (~24 VALU).
template<int CHS, int NCH, int WPB>
__global__ __launch_bounds__(64 * WPB, 4) void crf_chunk_dual(
    const float* __restrict__ emissions,    // [B, T, K]
    const int*   __restrict__ lengths32,
    const float* __restrict__ transitions,  // [K, K]
    unsigned int* __restrict__ Pout,        // [B][NCH][1024] bf16 as 512 dwords
    int*          __restrict__ toteOut)     // [B][NCH]
{
    constexpr int NSEG = CHS * KDIM / 256;   // 1KB DMA segments per chain
    __shared__ float lds_all[WPB][2][CHS * KDIM];
    const int wid  = threadIdx.x >> 6;
    const int lane = threadIdx.x & 63;
    const int n    = lane & 15;
    const int g    = (lane >> 4) & 3;
    const int w    = blockIdx.x * WPB + wid;
    const int b    = blockIdx.y;
    const int cA   = 2 * w, cB = 2 * w + 1;

    const int len = read_len(lengths32, b);
    const int tsA = 1 + cA * CHS, tsB = tsA + CHS;
    int cntA = len - tsA; cntA = cntA > CHS ? CHS : cntA;
    if (cntA <= 0) return;                    // adjacent pairing: cntB <= cntA
    int cntB = len - tsB; cntB = cntB > CHS ? CHS : cntB; if (cntB < 0) cntB = 0;
    const int shfB = (tsB + CHS > TDIM) ? (tsB - (TDIM - CHS)) : 0;  // {0,1}; shfA==0

    float* slA = &lds_all[wid][0][0];
    float* slB = &lds_all[wid][1][0];

    {   // DMA chain A
        const float* src = emissions + ((size_t)b * TDIM + tsA) * KDIM;
#pragma unroll
        for (int s = 0; s < NSEG; ++s)
            __builtin_amdgcn_global_load_lds(
                (const __attribute__((address_space(1))) void*)(src + s * 256 + lane * 4),
                (__attribute__((address_space(3))) void*)(slA + s * 256), 16, 0, 0);
    }
    if (cntB > 0) {  // DMA chain B
        const float* src = emissions + ((size_t)b * TDIM + (tsB - shfB)) * KDIM;
#pragma unroll
        for (int s = 0; s < NSEG; ++s)
            __builtin_amdgcn_global_load_lds(
                (const __attribute__((address_space(1))) void*)(src + s * 256 + lane * 4),
                (__attribute__((address_space(3))) void*)(slB + s * 256), 16, 0, 0);
    }

    // static E^T factors (A elem e <-> contraction row rho(g,e))
    f32x4 Ef00, Ef01, Ef10, Ef11;
#pragma unroll
    for (int e = 0; e < 4; ++e) {
        Ef00[e] = __expf(transitions[(4 * g + e) * KDIM + n]);
        Ef01[e] = __expf(transitions[(16 + 4 * g + e) * KDIM + n]);
        Ef10[e] = __expf(transitions[(4 * g + e) * KDIM + 16 + n]);
        Ef11[e] = __expf(transitions[(16 + 4 * g + e) * KDIM + 16 + n]);
    }

    asm volatile("s_waitcnt vmcnt(0)" ::: "memory");
    __builtin_amdgcn_sched_barrier(0);

    // exp pre-pass over both slices (dead-B garbage harmless, stays in-bounds)
    f32x4* mvAll = (f32x4*)slA;   // [2][CHS*KDIM] contiguous per wave
#pragma unroll
    for (int r = 0; r < 2 * NSEG; ++r) {
        f32x4 v = mvAll[r * 64 + lane];
#pragma unroll
        for (int e = 0; e < 4; ++e) v[e] = __expf(v[e]);
        mvAll[r * 64 + lane] = v;
    }
    asm volatile("s_waitcnt lgkmcnt(0)" ::: "memory");
    __builtin_amdgcn_sched_barrier(0);

    const f32x4* mvA = (const f32x4*)slA;
    const f32x4* mvB = (const f32x4*)slB;

    // chain states
    f32x4 CA0, CA1, CA2, CA3, CB0, CB1, CB2, CB3;
#pragma unroll
    for (int q = 0; q < 4; ++q) {
        float d = (4 * g + q == n) ? 1.0f : 0.0f;
        CA0[q] = d; CA3[q] = d; CA1[q] = 0.0f; CA2[q] = 0.0f;
        CB0[q] = d; CB3[q] = d; CB1[q] = 0.0f; CB2[q] = 0.0f;
    }
    float sfA = 1.0f, sfB = 1.0f;
    int pendA = 0, pendB = 0, toteA = 0, toteB = 0;
    const f32x4 zero = {0.0f, 0.0f, 0.0f, 0.0f};

    auto LDE = [&](const f32x4* mv, int tt, int shf, f32x4& e0, f32x4& e1) {
        tt += shf; if (tt > CHS - 1) tt = CHS - 1;
        e0 = mv[tt * 8 + g];
        e1 = mv[tt * 8 + 4 + g];
    };
    auto STEP = [&](f32x4& c0, f32x4& c1, f32x4& c2, f32x4& c3,
                    const f32x4& e0, const f32x4& e1) {
        f32x4 a00 = Ef00 * e0, a01 = Ef01 * e1, a10 = Ef10 * e0, a11 = Ef11 * e1;
        bf16x8 A0 = pk8(a00, a01), A1 = pk8(a10, a11);
        bf16x8 B0 = pk8(c0, c2),   B1 = pk8(c1, c3);
        c0 = __builtin_amdgcn_mfma_f32_16x16x32_bf16(A0, B0, zero, 0, 0, 0);
        c1 = __builtin_amdgcn_mfma_f32_16x16x32_bf16(A0, B1, zero, 0, 0, 0);
        c2 = __builtin_amdgcn_mfma_f32_16x16x32_bf16(A1, B0, zero, 0, 0, 0);
        c3 = __builtin_amdgcn_mfma_f32_16x16x32_bf16(A1, B1, zero, 0, 0, 0);
    };
    auto FOLD = [&](f32x4& e0, f32x4& e1, float sf, int& tote, int pend) {
#pragma unroll
        for (int e = 0; e < 4; ++e) { e0[e] *= sf; e1[e] *= sf; }
        tote += pend;
    };
    auto RESC = [&](const f32x4& c0, float& sf, int& pend) {
        int bits = __builtin_amdgcn_readfirstlane(__float_as_int(c0[0]));
        pend = ((bits >> 23) & 255) - 127;
        sf = __uint_as_float((unsigned)(127 - pend) << 23);
    };

    f32x4 eA0, eA1, eB0, eB1, nA0, nA1, nB0, nB1;
    LDE(mvA, 0, 0, eA0, eA1);
    if (cntB > 0) LDE(mvB, 0, shfB, eB0, eB1);

    if (cntB > 0) {                   // A is full (cntA == CHS)
        const int kg = cntB >> 2;     // joint full groups
        for (int gq = 0; gq < kg; ++gq) {
#pragma unroll
            for (int u = 0; u < 4; ++u) {
                const int tau = 4 * gq + u;
                LDE(mvA, tau + 1, 0,    nA0, nA1);
                LDE(mvB, tau + 1, shfB, nB0, nB1);
                if (u == 0) {
                    FOLD(eA0, eA1, sfA, toteA, pendA);
                    FOLD(eB0, eB1, sfB, toteB, pendB);
                }
                STEP(CA0, CA1, CA2, CA3, eA0, eA1);
                STEP(CB0, CB1, CB2, CB3, eB0, eB1);
                if (u == 3) { RESC(CA0, sfA, pendA); RESC(CB0, sfB, pendB); }
                eA0 = nA0; eA1 = nA1; eB0 = nB0; eB1 = nB1;
            }
        }
        for (int gq = kg; gq < CHS / 4; ++gq) {   // A-only remaining groups
#pragma unroll
            for (int u = 0; u < 4; ++u) {
                const int tau = 4 * gq + u;
                LDE(mvA, tau + 1, 0, nA0, nA1);
                if (u == 0) FOLD(eA0, eA1, sfA, toteA, pendA);
                STEP(CA0, CA1, CA2, CA3, eA0, eA1);
                if (u == 3) RESC(CA0, sfA, pendA);
                eA0 = nA0; eA1 = nA1;
            }
        }
        for (int tau = kg * 4; tau < cntB; ++tau) {  // B tail, per-step cadence
            LDE(mvB, tau + 1, shfB, nB0, nB1);
            FOLD(eB0, eB1, sfB, toteB, pendB);
            STEP(CB0, CB1, CB2, CB3, eB0, eB1);
            RESC(CB0, sfB, pendB);
            eB0 = nB0; eB1 = nB1;
        }
    } else {                          // A-only, possibly partial
        const int fg = cntA >> 2;
        for (int gq = 0; gq < fg; ++gq) {
#pragma unroll
            for (int u = 0; u < 4; ++u) {
                const int tau = 4 * gq + u;
                LDE(mvA, tau + 1, 0, nA0, nA1);
                if (u == 0) FOLD(eA0, eA1, sfA, toteA, pendA);
                STEP(CA0, CA1, CA2, CA3, eA0, eA1);
                if (u == 3) RESC(CA0, sfA, pendA);
                eA0 = nA0; eA1 = nA1;
            }
        }
        for (int tau = fg * 4; tau < cntA; ++tau) {
            LDE(mvA, tau + 1, 0, nA0, nA1);
            FOLD(eA0, eA1, sfA, toteA, pendA);
            STEP(CA0, CA1, CA2, CA3, eA0, eA1);
            RESC(CA0, sfA, pendA);
            eA0 = nA0; eA1 = nA1;
        }
    }

    // store: bf16 col-major, dword idx = col*16 + row/2
    auto STORE = [&](unsigned int* outP, const f32x4& c0, const f32x4& c1,
                     const f32x4& c2, const f32x4& c3) {
#pragma unroll
        for (int p = 0; p < 2; ++p) {
            int q = 2 * p;
            outP[n * 16        + (4 * g + q) / 2]      = pk_pair(c0[q], c0[q + 1]);
            outP[(16 + n) * 16 + (4 * g + q) / 2]      = pk_pair(c1[q], c1[q + 1]);
            outP[n * 16        + (16 + 4 * g + q) / 2] = pk_pair(c2[q], c2[q + 1]);
            outP[(16 + n) * 16 + (16 + 4 * g + q) / 2] = pk_pair(c3[q], c3[q + 1]);
        }
    };
    STORE(Pout + ((size_t)b * NCH + cA) * 512, CA0, CA1, CA2, CA3);
    if (lane == 0) toteOut[b * NCH + cA] = toteA;
    if (cntB > 0) {
        STORE(Pout + ((size_t)b * NCH + cB) * 512, CB0, CB1, CB2, CB3);
        if (lane == 0) toteOut[b * NCH + cB] = toteB;
    }
}

// ---------------- K2: chain chunk matrices through alpha ------------------
template<int NCH, int CHS>
__global__ __launch_bounds__(64) void crf_combine_kernel(
    const float* __restrict__ emissions,
    const int*   __restrict__ lengths32,
    const float* __restrict__ head_t,
    const float* __restrict__ last_t,
    const unsigned short* __restrict__ Pbuf,  // [B][NCH][1024] bf16 col-major
    const int*   __restrict__ toteBuf,
    float*       __restrict__ out)
{
    const int b    = blockIdx.x;
    const int lane = threadIdx.x;
    const int j    = lane & 31;

    const int len = read_len(lengths32, b);
    int nAlive = (len - 1 + CHS - 1) / CHS;
    if (nAlive > NCH) nAlive = NCH;

    float alpha = __expf(head_t[j] + emissions[(size_t)b * TDIM * KDIM + j]);
    int tote = 0;

    const char* base = (const char*)(Pbuf + (size_t)b * NCH * 1024);

    auto LOADC = [&](int cix, uint4 dst[4]) {
        int cc = cix < NCH ? cix : NCH - 1;
        const uint4* pc = (const uint4*)(base + (size_t)cc * 2048 + (size_t)j * 64);
#pragma unroll
        for (int w = 0; w < 4; ++w) dst[w] = pc[w];
    };

    uint4 cur[4], nx1[4];
    LOADC(0, cur);
    LOADC(1, nx1);

    for (int cix = 0; cix < nAlive; ++cix) {
        uint4 nx2[4];
        LOADC(cix + 2, nx2);

        float a0 = 0.0f, a1 = 0.0f;
#pragma unroll
        for (int w = 0; w < 4; ++w) {
            unsigned d[4] = {cur[w].x, cur[w].y, cur[w].z, cur[w].w};
#pragma unroll
            for (int h = 0; h < 4; ++h) {
                int r = w * 8 + h * 2;
                float plo = __uint_as_float(d[h] << 16);           // row r,   col j
                float phi = __uint_as_float(d[h] & 0xffff0000u);   // row r+1, col j
                float al  = __int_as_float(__builtin_amdgcn_readlane(__float_as_int(alpha), r));
                float ah  = __int_as_float(__builtin_amdgcn_readlane(__float_as_int(alpha), r + 1));
                a0 = fmaf(plo, al, a0);
                a1 = fmaf(phi, ah, a1);
            }
        }
        float acc = a0 + a1;
        int bits = __builtin_amdgcn_readfirstlane(__float_as_int(acc));
        int s = ((bits >> 23) & 255) - 127;
        alpha = acc * __uint_as_float((unsigned)(127 - s) << 23);
        tote += s + toteBuf[b * NCH + cix];
#pragma unroll
        for (int w = 0; w < 4; ++w) { cur[w] = nx1[w]; nx1[w] = nx2[w]; }
    }

    float pp = alpha * __expf(last_t[j]);
#pragma unroll
    for (int mm = 16; mm >= 1; mm >>= 1)
        pp += __shfl_xor(pp, mm, 64);

    if (lane == 0)
        out[b] = __logf(pp) + (float)tote * 0.69314718055994531f;
}

extern "C" void kernel_launch(void* const* d_in, const int* in_sizes, int n_in,
                              void* d_out, int out_size, void* d_ws, size_t ws_size,
                              hipStream_t stream)
{
    const float* emissions   = (const float*)d_in[0];
    const int*   lengths     = (const int*)d_in[1];
    const float* transitions = (const float*)d_in[2];
    const float* head_t      = (const float*)d_in[3];
    const float* last_t      = (const float*)d_in[4];
    float* out = (float*)d_out;
    const int B = out_size;  // 512

    unsigned int* Pbuf = (unsigned int*)d_ws;

    const size_t need32 = (size_t)B * 32 * 2048 + (size_t)B * 32 * 4;
    if (ws_size >= need32) {
        int* toteBf = (int*)((char*)d_ws + (size_t)B * 32 * 2048);
        // CHS=32, NCH=32, 2 chains/wave, 4 waves/block: grid (32/(2*4)=4, B)
        dim3 g1(4, B);
        crf_chunk_dual<32, 32, 4><<<g1, 256, 0, stream>>>(emissions, lengths, transitions, Pbuf, toteBf);
        crf_combine_kernel<32, 32><<<B, 64, 0, stream>>>(emissions, lengths, head_t, last_t,
                                                         (const unsigned short*)Pbuf, toteBf, out);
    } else {
        int* toteBf = (int*)((char*)d_ws + (size_t)B * 16 * 2048);
        // CHS=64, NCH=16, 2 chains/wave, 4 waves/block: grid (16/(2*4)=2, B)
        dim3 g1(2, B);
        crf_chunk_dual<64, 16, 4><<<g1, 256, 0, stream>>>(emissions, lengths, transitions, Pbuf, toteBf);
        crf_combine_kernel<16, 64><<<B, 64, 0, stream>>>(emissions, lengths, head_t, last_t,
                                                         (const unsigned short*)Pbuf, toteBf, out);
    }
}